// Round 7
// baseline (598.787 us; speedup 1.0000x reference)
//
#include <hip/hip_runtime.h>
#include <cstdint>
#include <cstddef>

#define DEVINL __device__ __forceinline__

typedef __bf16 bf16x8 __attribute__((ext_vector_type(8)));
typedef float f32x4 __attribute__((ext_vector_type(4)));

static constexpr int NN = 10000;     // nodes
static constexpr int NE = 80000;     // edges
static constexpr int IN_DIM = 1024;
static constexpr int HID = 4096;
static constexpr int OUTD = 256;
static constexpr int M_PAD = 10112;  // 79*128 (also 158*64)

// fp32 -> bf16 round-nearest-even
DEVINL unsigned short f2bf(float f) {
  unsigned int u = __builtin_bit_cast(unsigned int, f);
  u += 0x7fffu + ((u >> 16) & 1u);
  return (unsigned short)(u >> 16);
}
DEVINL float bf2f(unsigned short h) {
  unsigned int u = ((unsigned int)h) << 16;
  return __builtin_bit_cast(float, u);
}

// async global->LDS, 16B per lane; LDS dest is wave-uniform base + lane*16
DEVINL void ld_lds16(const void* g, void* l) {
  __builtin_amdgcn_global_load_lds(
      (const __attribute__((address_space(1))) unsigned int*)g,
      (__attribute__((address_space(3))) unsigned int*)l, 16, 0, 0);
}

// ---------------- fused prep: conv_w1 + conv_w2 + x->bf16 + degree count ----------------
static constexpr int PREP_B1 = 8192;
static constexpr int PREP_B2 = PREP_B1 + 2048;
static constexpr int PREP_B3 = PREP_B2 + 10000;
static constexpr int PREP_NB = PREP_B3 + 313;

__global__ __launch_bounds__(256) void prep_kernel(
    const float* __restrict__ W1l, const float* __restrict__ W1r,
    const float* __restrict__ W2l, const float* __restrict__ W2r,
    const float* __restrict__ x, const int* __restrict__ dst,
    unsigned short* __restrict__ w1cat, unsigned short* __restrict__ w2cat,
    unsigned short* __restrict__ x_bf, int* __restrict__ deg) {
  int b = blockIdx.x;
  int t = threadIdx.x;
  if (b < PREP_B1) {  // w1cat [4096][2048]: row n = [W1_l row n | W1_r row n]
    int g = b * 256 + t;
    int n = g >> 9;
    int kg = g & 511;
    const float* s = (kg < 256) ? (W1l + (size_t)n * 1024 + kg * 4)
                                : (W1r + (size_t)n * 1024 + (kg - 256) * 4);
    float4 v = *(const float4*)s;
    ushort4 p = {f2bf(v.x), f2bf(v.y), f2bf(v.z), f2bf(v.w)};
    ((ushort4*)w1cat)[g] = p;
  } else if (b < PREP_B2) {  // w2cat [512][4096]: rows 0..255 = W2_l, 256..511 = W2_r
    int g = (b - PREP_B1) * 256 + t;
    int n = g >> 10;
    int kg = g & 1023;
    const float* s = (n < 256) ? (W2l + (size_t)n * 4096 + kg * 4)
                               : (W2r + (size_t)(n - 256) * 4096 + kg * 4);
    float4 v = *(const float4*)s;
    ushort4 p = {f2bf(v.x), f2bf(v.y), f2bf(v.z), f2bf(v.w)};
    ((ushort4*)w2cat)[g] = p;
  } else if (b < PREP_B3) {  // x -> bf16, [10000][1024]
    int g = (b - PREP_B2) * 256 + t;
    int i = g >> 8;
    int kg = g & 255;
    float4 v = ((const float4*)(x + (size_t)i * IN_DIM))[kg];
    ushort4 p = {f2bf(v.x), f2bf(v.y), f2bf(v.z), f2bf(v.w)};
    ((ushort4*)(x_bf + (size_t)i * IN_DIM))[kg] = p;
  } else {  // degree count
    int e = (b - PREP_B3) * 256 + t;
    if (e < NE) atomicAdd(&deg[dst[e]], 1);
  }
}

// one-block exclusive scan over NN degrees -> offs[0..NN] and cursor copy cur[]
__global__ __launch_bounds__(1024) void scan_kernel(const int* __restrict__ deg,
                                                    int* __restrict__ offs,
                                                    int* __restrict__ cur) {
  __shared__ int part[1024];
  constexpr int NPT = 10;  // 1024*10 = 10240 >= NN
  int t = threadIdx.x;
  int base = t * NPT;
  int s = 0;
  for (int j = 0; j < NPT; ++j) {
    int n = base + j;
    s += (n < NN) ? deg[n] : 0;
  }
  part[t] = s;
  __syncthreads();
  for (int o = 1; o < 1024; o <<= 1) {  // Hillis-Steele inclusive scan
    int v = (t >= o) ? part[t - o] : 0;
    __syncthreads();
    part[t] += v;
    __syncthreads();
  }
  int pre = (t > 0) ? part[t - 1] : 0;
  for (int j = 0; j < NPT; ++j) {
    int n = base + j;
    if (n < NN) {
      offs[n] = pre;
      cur[n] = pre;
      pre += deg[n];
    }
  }
  if (t == 1023) offs[NN] = part[1023];  // == NE
}

// bin edges: csr[cur[dst]++] = src  (cur pre-seeded with offs by scan)
__global__ void bin_kernel(const int* __restrict__ src, const int* __restrict__ dst,
                           int* __restrict__ cur, int* __restrict__ csr) {
  int e = blockIdx.x * 256 + threadIdx.x;
  if (e < NE) {
    int p = atomicAdd(&cur[dst[e]], 1);
    csr[p] = src[e];
  }
}

// ---------------- layer-1 gather (bf16 source): A1 = mean_agg(x) only ----------------
__global__ __launch_bounds__(256) void gather1_kernel(unsigned short* __restrict__ x_bf,
                                                      const int* __restrict__ offs,
                                                      const int* __restrict__ csr,
                                                      unsigned short* __restrict__ A1) {
  int i = blockIdx.x;
  int t = threadIdx.x;  // 256 threads x ushort4 = 1024 bf16 = one row
  unsigned short* row = A1 + (size_t)i * 1024;
  if (i >= NN) {
    ushort4 z = {0, 0, 0, 0};
    ((ushort4*)row)[t] = z;
    ((ushort4*)(x_bf + (size_t)i * 1024))[t] = z;
    return;
  }
  int beg = offs[i], end = offs[i + 1];
  float4 a0 = {0.f, 0.f, 0.f, 0.f}, a1 = {0.f, 0.f, 0.f, 0.f};
  int j = beg;
  for (; j + 2 <= end; j += 2) {
    int s0 = __builtin_amdgcn_readfirstlane(csr[j]);
    int s1 = __builtin_amdgcn_readfirstlane(csr[j + 1]);
    ushort4 u0 = ((const ushort4*)(x_bf + (size_t)s0 * IN_DIM))[t];
    ushort4 u1 = ((const ushort4*)(x_bf + (size_t)s1 * IN_DIM))[t];
    a0.x += bf2f(u0.x); a0.y += bf2f(u0.y); a0.z += bf2f(u0.z); a0.w += bf2f(u0.w);
    a1.x += bf2f(u1.x); a1.y += bf2f(u1.y); a1.z += bf2f(u1.z); a1.w += bf2f(u1.w);
  }
  if (j < end) {
    int s0 = __builtin_amdgcn_readfirstlane(csr[j]);
    ushort4 u0 = ((const ushort4*)(x_bf + (size_t)s0 * IN_DIM))[t];
    a0.x += bf2f(u0.x); a0.y += bf2f(u0.y); a0.z += bf2f(u0.z); a0.w += bf2f(u0.w);
  }
  float inv = 1.0f / (float)max(end - beg, 1);
  ushort4 pa = {f2bf((a0.x + a1.x) * inv), f2bf((a0.y + a1.y) * inv),
                f2bf((a0.z + a1.z) * inv), f2bf((a0.w + a1.w) * inv)};
  ((ushort4*)row)[t] = pa;
}

// ---------------- GEMM1: 128x128, A direct global->VGPR, B LDS-dbuf counted-vmcnt ------
// R6 post-mortem: counted-vmcnt depth-2 gave only +2-6% (MfmaUtil 33.8%) -> latency was
// NOT the binder. Per-CU per-K-tile arithmetic: LDS demand (reads 128KB + staged writes
// 64KB ~ 1715 cyc @112B/cyc) > MFMA demand (1240 cyc) -> LDS pipe binds. Fix: A-frags
// load DIRECTLY global->VGPR (A panel is L3/L2-resident; FETCH 260MB ~= B re-reads).
// Fragment equivalence: LDS path delivered af[i] = A[row][k0 + kk*32 + quad*8 .. +8];
// direct load reproduces it exactly (aRow bakes row*1024 + quad*8).
// LDS now B-only dbuf 32KB -> 3-5 blocks/CU (was 2); LDS traffic per CU-tile halved.
// vmcnt protocol per tile t: af(t) loads FIRST (sched_barrier-pinned), then B-stage(t+1),
// then vmcnt(12) = retire B(t) only, keep af(t)8 + B(t+1)4 in flight; the compiler then
// inserts its own vmcnt(4) before the first MFMA use of af (retiring af only, B(t+1)
// still in flight). Last tile: no stage -> vmcnt(8). Never drains a just-issued load.
// Hazards: stage into buf (t+1)&1 at top of t: that buffer's reads ended before t-1's
// closing barrier. bv ds_reads sit below barrier+sched_barrier(0) (R6-proven pattern).
__global__ __launch_bounds__(256) void gemm1_areg_kernel(
    const unsigned short* __restrict__ A,    // A1  (k < 1024), row stride 1024
    const unsigned short* __restrict__ A2,   // x_bf (k >= 1024), row stride 1024
    const unsigned short* __restrict__ Bt,   // w1cat [4096][2048]
    const float* __restrict__ bias,
    unsigned short* __restrict__ C) {
  constexpr int BM = 128, BN = 128, BK = 64;
  constexpr int K = 2048, N = 4096;
  constexpr int NT = K / BK;  // 32
  constexpr int NUMM = 79, NUMN = 32, GM = 32, NPG = GM * NUMN;
  constexpr int TSZ = BN * BK;  // B tile: 8192 bf16 = 16KB

  __shared__ unsigned short Bsm[2 * TSZ];  // 32KB total

  // grouped swizzle on grid.x (identical to baseline)
  const int pid = blockIdx.x;
  const int gid = pid / NPG;
  const int first_m = gid * GM;
  const int sz = (NUMM - first_m < GM) ? (NUMM - first_m) : GM;
  const int local = pid % NPG;
  const int pm = first_m + local % sz;
  const int pn = local / sz;
  const long tm0 = (long)pm * BM;
  const long tn0 = (long)pn * BN;

  const int tid = threadIdx.x;
  const int lane = tid & 63;
  const int wave = tid >> 6;
  const int quad = lane >> 4;
  const int l16 = lane & 15;
  const int l7 = l16 & 7;
  const int wm = (wave % 2) * 64;  // 2x2 wave layout
  const int wn = (wave / 2) * 64;

  f32x4 acc[4][4];
#pragma unroll
  for (int i = 0; i < 4; ++i)
#pragma unroll
    for (int j = 0; j < 4; ++j) acc[i][j] = (f32x4){0.f, 0.f, 0.f, 0.f};

  // B staging map (unchanged): chunk c = s*256+tid; row r=c/8; slot=c%8; g=slot^(r&7)
  size_t bOff[4];
#pragma unroll
  for (int s = 0; s < 4; ++s) {
    int c = s * 256 + tid;
    int r = c >> 3;
    int g = (c & 7) ^ (r & 7);
    bOff[s] = (size_t)(tn0 + r) * K + g * 8;
  }

  // A-frag per-lane element offsets: row*(K/2=1024) + quad*8 baked in
  size_t aRow[4];
#pragma unroll
  for (int i = 0; i < 4; ++i)
    aRow[i] = (size_t)(tm0 + wm + i * 16 + l16) * 1024 + quad * 8;

#define STAGE_B1(kt, bb)                                                         \
  {                                                                              \
    const int k0_ = (kt)*BK;                                                     \
    _Pragma("unroll") for (int q_ = 0; q_ < 4; ++q_)                             \
        ld_lds16(Bt + bOff[q_] + k0_, Bsm + (bb)*TSZ + q_ * 2048 + wave * 512);  \
  }

  STAGE_B1(0, 0)

  for (int t = 0; t < NT; ++t) {
    // A-frags for THIS tile, direct from global (L2/L3-warm panel) — issued first
    const unsigned short* As = (t < NT / 2) ? A : A2;
    const int ka = (t & (NT / 2 - 1)) * BK;
    bf16x8 af[2][4];
#pragma unroll
    for (int kk = 0; kk < 2; ++kk)
#pragma unroll
      for (int i = 0; i < 4; ++i)
        af[kk][i] = *(const bf16x8*)(As + aRow[i] + ka + kk * 32);
    __builtin_amdgcn_sched_barrier(0);  // pin: af loads BEFORE the stage builtins

    if (t + 1 < NT) {
      STAGE_B1(t + 1, (t + 1) & 1)
      // retire B(t) (issued one full tile ago, ~free); keep af(t)=8 + B(t+1)=4 in flight
      asm volatile("s_waitcnt vmcnt(12)" ::: "memory");
    } else {
      asm volatile("s_waitcnt vmcnt(8)" ::: "memory");  // retire B(t); keep af(t)
    }
    __builtin_amdgcn_s_barrier();       // raw: B tile t visible in ALL waves
    __builtin_amdgcn_sched_barrier(0);  // keep bv ds_reads below the barrier

    const unsigned short* Bs = Bsm + (t & 1) * TSZ;
#pragma unroll
    for (int kk = 0; kk < 2; ++kk) {
      const int p = (kk * 4 + quad) ^ l7;
      bf16x8 bv[4];
#pragma unroll
      for (int j = 0; j < 4; ++j)
        bv[j] = *(const bf16x8*)(Bs + (wn + j * 16 + l16) * BK + p * 8);
#pragma unroll
      for (int i = 0; i < 4; ++i)
#pragma unroll
        for (int j = 0; j < 4; ++j)
          acc[i][j] = __builtin_amdgcn_mfma_f32_16x16x32_bf16(af[kk][i], bv[j], acc[i][j], 0, 0, 0);
    }
    __builtin_amdgcn_s_barrier();  // all B reads of this buf done before overwrite
    __builtin_amdgcn_sched_barrier(0);
  }
#undef STAGE_B1

  // epilogue: relu(acc + bias) -> bf16; C/D layout col = lane&15, row = quad*4 + reg
#pragma unroll
  for (int i = 0; i < 4; ++i) {
    long m0 = tm0 + wm + i * 16 + quad * 4;
#pragma unroll
    for (int j = 0; j < 4; ++j) {
      int n = (int)tn0 + wn + j * 16 + l16;
      float bvs = bias[n];
#pragma unroll
      for (int r = 0; r < 4; ++r) {
        float v = fmaxf(acc[i][j][r] + bvs, 0.0f);
        C[(size_t)(m0 + r) * N + n] = f2bf(v);
      }
    }
  }
}

// ---------------- bf16 MFMA GEMM, templated (kept for GEMM2) ----------------
// NOTE (R5): BM 64->32 for GEMM2 regressed (~+15 us). Keep BM=64.
// NOTE (R2-R6): GEMM1 session evidence — 256^2 phase-splits regressed (242-254 us);
// counted-vmcnt depth-2 on 128^2 = small win (219.7 us); LDS-BW is the diagnosed binder.
template <int BM, int BN, int BK, int K, int KSPLIT, int N, int NUMM, int NUMN, int GM,
          int EPI, int NWY, bool ASPLIT>
__global__ __launch_bounds__(256) void gemm_kernel(const unsigned short* __restrict__ A,
                                                   const unsigned short* __restrict__ A2,
                                                   const unsigned short* __restrict__ Bt,
                                                   const float* __restrict__ bias,
                                                   void* __restrict__ C0out) {
  constexpr int MGR = 4 / NWY;            // waves along m
  constexpr int MI = BM / 16 / MGR;       // 16-row tiles per wave
  constexpr int NI = 4;                   // 16-col tiles per wave (BN = NWY*64)
  constexpr int CPR = BK / 8;             // 16B chunks per LDS row
  constexpr int SA = BM * CPR / 256;      // staging rounds for A (256 thr x 16B)
  constexpr int SB = BN * CPR / 256;
  constexpr int KK = BK / 32;             // MFMA k-steps per tile
  constexpr int KS = K / KSPLIT;          // K range per split
  constexpr int AS = ASPLIT ? K / 2 : K;  // A row stride
  __shared__ unsigned short Asm[BM * BK];
  __shared__ unsigned short Bsm[BN * BK];

  constexpr int NPG = GM * NUMN;
  const int pid = blockIdx.x;
  const int gid = pid / NPG;
  const int first_m = gid * GM;
  const int sz = (NUMM - first_m < GM) ? (NUMM - first_m) : GM;
  const int local = pid % NPG;
  const int pm = first_m + local % sz;
  const int pn = local / sz;
  const int koff = (KSPLIT > 1) ? (int)blockIdx.y * KS : 0;

  const int tid = threadIdx.x;
  const int lane = tid & 63;
  const int wave = tid >> 6;
  const int quad = lane >> 4;
  const int l16 = lane & 15;
  const int wm = (wave % MGR) * (BM / MGR);
  const int wn = (wave / MGR) * 64;
  const long tm0 = (long)pm * BM;
  const long tn0 = (long)pn * BN;

  f32x4 acc[MI][NI];
#pragma unroll
  for (int i = 0; i < MI; ++i)
#pragma unroll
    for (int j = 0; j < NI; ++j) acc[i][j] = (f32x4){0.f, 0.f, 0.f, 0.f};

  size_t aOff[SA];
  unsigned short* aDst[SA];
  const unsigned short* bSrc[SB];
  unsigned short* bDst[SB];
#pragma unroll
  for (int s = 0; s < SA; ++s) {
    int c = s * 256 + wave * 64 + lane;
    int r = c / CPR;
    int g = (c % CPR) ^ (r & 7);
    aOff[s] = (size_t)(tm0 + r) * AS + koff + g * 8;
    aDst[s] = Asm + s * 2048 + wave * 512;  // wave-uniform base
  }
#pragma unroll
  for (int s = 0; s < SB; ++s) {
    int c = s * 256 + wave * 64 + lane;
    int r = c / CPR;
    int g = (c % CPR) ^ (r & 7);
    bSrc[s] = Bt + (size_t)(tn0 + r) * K + koff + g * 8;
    bDst[s] = Bsm + s * 2048 + wave * 512;
  }

  const int l7 = l16 & 7;

  for (int k0 = 0; k0 < KS; k0 += BK) {
    const unsigned short* ab = (!ASPLIT || k0 < K / 2) ? A : A2;
    const int ka = ASPLIT ? (k0 & (K / 2 - 1)) : k0;
#pragma unroll
    for (int s = 0; s < SA; ++s) ld_lds16(ab + aOff[s] + ka, aDst[s]);
#pragma unroll
    for (int s = 0; s < SB; ++s) ld_lds16(bSrc[s] + k0, bDst[s]);
    __syncthreads();  // drains vmcnt -> LDS tiles complete

#pragma unroll
    for (int kk = 0; kk < KK; ++kk) {
      const int p = (kk * 4 + quad) ^ l7;  // physical chunk for this frag
      bf16x8 af[MI], bv[NI];
#pragma unroll
      for (int i = 0; i < MI; ++i) {
        int ra = wm + i * 16 + l16;
        af[i] = *(const bf16x8*)(Asm + ra * BK + p * 8);
      }
#pragma unroll
      for (int j = 0; j < NI; ++j) {
        int rb = wn + j * 16 + l16;
        bv[j] = *(const bf16x8*)(Bsm + rb * BK + p * 8);
      }
#pragma unroll
      for (int i = 0; i < MI; ++i)
#pragma unroll
        for (int j = 0; j < NI; ++j)
          acc[i][j] = __builtin_amdgcn_mfma_f32_16x16x32_bf16(af[i], bv[j], acc[i][j], 0, 0, 0);
    }
    __syncthreads();  // LDS reads done before next stage overwrites
  }

  if (EPI == 1) {
    unsigned short* C = (unsigned short*)C0out;
#pragma unroll
    for (int i = 0; i < MI; ++i) {
      long m0 = tm0 + wm + i * 16 + quad * 4;
#pragma unroll
      for (int j = 0; j < NI; ++j) {
        int n = (int)tn0 + wn + j * 16 + l16;
        float bvs = bias[n];
#pragma unroll
        for (int r = 0; r < 4; ++r) {
          float v = acc[i][j][r] + bvs;
          v = fmaxf(v, 0.0f);
          C[(size_t)(m0 + r) * N + n] = f2bf(v);
        }
      }
    }
  } else {  // EPI == 3: bf16 partial, slab per grid.y
    unsigned short* C = (unsigned short*)C0out + (size_t)blockIdx.y * NUMM * BM * N;
#pragma unroll
    for (int i = 0; i < MI; ++i) {
      long m0 = tm0 + wm + i * 16 + quad * 4;
#pragma unroll
      for (int j = 0; j < NI; ++j) {
        int n = (int)tn0 + wn + j * 16 + l16;
#pragma unroll
        for (int r = 0; r < 4; ++r) C[(size_t)(m0 + r) * N + n] = f2bf(acc[i][j][r]);
      }
    }
  }
}

// ---------------- layer-2 gather + bias + p_r + log_softmax (fused, reads split-K P) ----
__global__ __launch_bounds__(128) void gather2_final_kernel(const unsigned short* __restrict__ P,
                                                            const int* __restrict__ offs,
                                                            const int* __restrict__ csr,
                                                            const float* __restrict__ b2,
                                                            float* __restrict__ out) {
  int i = blockIdx.x;
  int t = threadIdx.x;  // 0..127
  const unsigned short* P1 = P + (size_t)M_PAD * 512;
  int beg = offs[i], end = offs[i + 1];
  float a0 = 0.f, a1 = 0.f, c0 = 0.f, c1 = 0.f;
  int j = beg;
  for (; j + 2 <= end; j += 2) {
    int s0 = __builtin_amdgcn_readfirstlane(csr[j]);
    int s1 = __builtin_amdgcn_readfirstlane(csr[j + 1]);
    unsigned int u0 = ((const unsigned int*)(P + (size_t)s0 * 512))[t];
    unsigned int w0 = ((const unsigned int*)(P1 + (size_t)s0 * 512))[t];
    unsigned int u1 = ((const unsigned int*)(P + (size_t)s1 * 512))[t];
    unsigned int w1 = ((const unsigned int*)(P1 + (size_t)s1 * 512))[t];
    a0 += bf2f((unsigned short)(u0 & 0xffffu)) + bf2f((unsigned short)(w0 & 0xffffu));
    a1 += bf2f((unsigned short)(u0 >> 16)) + bf2f((unsigned short)(w0 >> 16));
    c0 += bf2f((unsigned short)(u1 & 0xffffu)) + bf2f((unsigned short)(w1 & 0xffffu));
    c1 += bf2f((unsigned short)(u1 >> 16)) + bf2f((unsigned short)(w1 >> 16));
  }
  if (j < end) {
    int s0 = __builtin_amdgcn_readfirstlane(csr[j]);
    unsigned int u0 = ((const unsigned int*)(P + (size_t)s0 * 512))[t];
    unsigned int w0 = ((const unsigned int*)(P1 + (size_t)s0 * 512))[t];
    a0 += bf2f((unsigned short)(u0 & 0xffffu)) + bf2f((unsigned short)(w0 & 0xffffu));
    a1 += bf2f((unsigned short)(u0 >> 16)) + bf2f((unsigned short)(w0 >> 16));
  }
  float inv = 1.0f / (float)max(end - beg, 1);
  float2 bv = ((const float2*)b2)[t];
  // self p_r term: cols 256+2t, 257+2t of both partial slabs
  unsigned int su = ((const unsigned int*)(P + (size_t)i * 512))[128 + t];
  unsigned int sw = ((const unsigned int*)(P1 + (size_t)i * 512))[128 + t];
  float pv0 = bf2f((unsigned short)(su & 0xffffu)) + bf2f((unsigned short)(sw & 0xffffu));
  float pv1 = bf2f((unsigned short)(su >> 16)) + bf2f((unsigned short)(sw >> 16));
  float v0 = (a0 + c0) * inv + bv.x + pv0;
  float v1 = (a1 + c1) * inv + bv.y + pv1;

  __shared__ float sm[2], ss[2];
  int w = t >> 6;
  float m = fmaxf(v0, v1);
#pragma unroll
  for (int o = 32; o > 0; o >>= 1) m = fmaxf(m, __shfl_xor(m, o, 64));
  if ((t & 63) == 0) sm[w] = m;
  __syncthreads();
  m = fmaxf(sm[0], sm[1]);

  float s = __expf(v0 - m) + __expf(v1 - m);
#pragma unroll
  for (int o = 32; o > 0; o >>= 1) s += __shfl_xor(s, o, 64);
  if ((t & 63) == 0) ss[w] = s;
  __syncthreads();
  float ls = logf(ss[0] + ss[1]);

  float2 o2 = {v0 - m - ls, v1 - m - ls};
  ((float2*)(out + (size_t)i * OUTD))[t] = o2;
}

// ---------------- workspace layout (bytes) ----------------
static constexpr size_t OFF_A1 = 0;
static constexpr size_t OFF_XBF = OFF_A1 + (size_t)M_PAD * 1024 * 2;
static constexpr size_t OFF_W1 = OFF_XBF + (size_t)M_PAD * 1024 * 2;
static constexpr size_t OFF_HB = OFF_W1 + (size_t)HID * 2048 * 2;
static constexpr size_t OFF_W2 = OFF_HB + (size_t)M_PAD * HID * 2;
static constexpr size_t OFF_DEG = OFF_W2 + (size_t)512 * HID * 2;
static constexpr size_t OFF_OFFS = OFF_DEG + (size_t)NN * 4;
static constexpr size_t OFF_CUR = OFF_OFFS + (size_t)(NN + 4) * 4;
static constexpr size_t OFF_CSR = OFF_CUR + (size_t)NN * 4;
static constexpr size_t OFF_P = OFF_A1;  // [2][M_PAD][512] bf16 = 20.7 MB, fits A1 region

extern "C" void kernel_launch(void* const* d_in, const int* in_sizes, int n_in,
                              void* d_out, int out_size, void* d_ws, size_t ws_size,
                              hipStream_t stream) {
  const float* x = (const float*)d_in[0];
  const int* ei = (const int*)d_in[1];
  const int* src = ei;
  const int* dst = ei + NE;
  const float* W1_l = (const float*)d_in[2];
  const float* b1_l = (const float*)d_in[3];
  const float* W1_r = (const float*)d_in[4];
  const float* W2_l = (const float*)d_in[5];
  const float* b2_l = (const float*)d_in[6];
  const float* W2_r = (const float*)d_in[7];
  float* out = (float*)d_out;

  char* ws = (char*)d_ws;
  unsigned short* A1 = (unsigned short*)(ws + OFF_A1);
  unsigned short* x_bf = (unsigned short*)(ws + OFF_XBF);
  unsigned short* w1cat = (unsigned short*)(ws + OFF_W1);
  unsigned short* h_b = (unsigned short*)(ws + OFF_HB);
  unsigned short* w2cat = (unsigned short*)(ws + OFF_W2);
  int* deg = (int*)(ws + OFF_DEG);
  int* offs = (int*)(ws + OFF_OFFS);
  int* cur = (int*)(ws + OFF_CUR);
  int* csr = (int*)(ws + OFF_CSR);
  unsigned short* P = (unsigned short*)(ws + OFF_P);

  // zero degree counters (ws is poisoned 0xAA before every call)
  hipMemsetAsync(deg, 0, (size_t)NN * 4, stream);

  prep_kernel<<<PREP_NB, 256, 0, stream>>>(W1_l, W1_r, W2_l, W2_r, x, dst,
                                           w1cat, w2cat, x_bf, deg);
  scan_kernel<<<1, 1024, 0, stream>>>(deg, offs, cur);
  bin_kernel<<<(NE + 255) / 256, 256, 0, stream>>>(src, dst, cur, csr);

  gather1_kernel<<<M_PAD, 256, 0, stream>>>(x_bf, offs, csr, A1);

  // h = relu([A1 | x_bf] @ w1cat^T + b1) -> bf16 [10112][4096]
  // A-direct-to-reg + B LDS-dbuf counted vmcnt (32KB LDS, 3-5 blocks/CU)
  gemm1_areg_kernel<<<79 * 32, 256, 0, stream>>>(A1, x_bf, w1cat, b1_l, h_b);

  // split-K=2, BM=64 (R2-verified config): P[s] -> bf16 [2][M][512]
  gemm_kernel<64, 256, 64, 4096, 2, 512, 158, 2, 1, 3, 4, false>
      <<<dim3(158 * 2, 2), 256, 0, stream>>>(h_b, nullptr, w2cat, nullptr, P);

  gather2_final_kernel<<<NN, 128, 0, stream>>>(P, offs, csr, b2_l, out);
}

// Round 8
// 458.044 us; speedup vs baseline: 1.3073x; 1.3073x over previous
//
#include <hip/hip_runtime.h>
#include <cstdint>
#include <cstddef>

#define DEVINL __device__ __forceinline__

typedef __bf16 bf16x8 __attribute__((ext_vector_type(8)));
typedef float f32x4 __attribute__((ext_vector_type(4)));

static constexpr int NN = 10000;     // nodes
static constexpr int NE = 80000;     // edges
static constexpr int IN_DIM = 1024;
static constexpr int HID = 4096;
static constexpr int OUTD = 256;
static constexpr int M_PAD = 10112;  // 79*128 (also 158*64)

// fp32 -> bf16 round-nearest-even
DEVINL unsigned short f2bf(float f) {
  unsigned int u = __builtin_bit_cast(unsigned int, f);
  u += 0x7fffu + ((u >> 16) & 1u);
  return (unsigned short)(u >> 16);
}
DEVINL float bf2f(unsigned short h) {
  unsigned int u = ((unsigned int)h) << 16;
  return __builtin_bit_cast(float, u);
}
DEVINL float bflo(unsigned int u) { return bf2f((unsigned short)(u & 0xffffu)); }
DEVINL float bfhi(unsigned int u) { return bf2f((unsigned short)(u >> 16)); }

// async global->LDS, 16B per lane; LDS dest is wave-uniform base + lane*16
DEVINL void ld_lds16(const void* g, void* l) {
  __builtin_amdgcn_global_load_lds(
      (const __attribute__((address_space(1))) unsigned int*)g,
      (__attribute__((address_space(3))) unsigned int*)l, 16, 0, 0);
}

// ---------------- fused prep: conv_w1 + conv_w2 + x->bf16 + degree count ----------------
static constexpr int PREP_B1 = 8192;
static constexpr int PREP_B2 = PREP_B1 + 2048;
static constexpr int PREP_B3 = PREP_B2 + 10000;
static constexpr int PREP_NB = PREP_B3 + 313;

__global__ __launch_bounds__(256) void prep_kernel(
    const float* __restrict__ W1l, const float* __restrict__ W1r,
    const float* __restrict__ W2l, const float* __restrict__ W2r,
    const float* __restrict__ x, const int* __restrict__ dst,
    unsigned short* __restrict__ w1cat, unsigned short* __restrict__ w2cat,
    unsigned short* __restrict__ x_bf, int* __restrict__ deg) {
  int b = blockIdx.x;
  int t = threadIdx.x;
  if (b < PREP_B1) {  // w1cat [4096][2048]: row n = [W1_l row n | W1_r row n]
    int g = b * 256 + t;
    int n = g >> 9;
    int kg = g & 511;
    const float* s = (kg < 256) ? (W1l + (size_t)n * 1024 + kg * 4)
                                : (W1r + (size_t)n * 1024 + (kg - 256) * 4);
    float4 v = *(const float4*)s;
    ushort4 p = {f2bf(v.x), f2bf(v.y), f2bf(v.z), f2bf(v.w)};
    ((ushort4*)w1cat)[g] = p;
  } else if (b < PREP_B2) {  // w2cat [512][4096]: rows 0..255 = W2_l, 256..511 = W2_r
    int g = (b - PREP_B1) * 256 + t;
    int n = g >> 10;
    int kg = g & 1023;
    const float* s = (n < 256) ? (W2l + (size_t)n * 4096 + kg * 4)
                               : (W2r + (size_t)(n - 256) * 4096 + kg * 4);
    float4 v = *(const float4*)s;
    ushort4 p = {f2bf(v.x), f2bf(v.y), f2bf(v.z), f2bf(v.w)};
    ((ushort4*)w2cat)[g] = p;
  } else if (b < PREP_B3) {  // x -> bf16, [10000][1024]
    int g = (b - PREP_B2) * 256 + t;
    int i = g >> 8;
    int kg = g & 255;
    float4 v = ((const float4*)(x + (size_t)i * IN_DIM))[kg];
    ushort4 p = {f2bf(v.x), f2bf(v.y), f2bf(v.z), f2bf(v.w)};
    ((ushort4*)(x_bf + (size_t)i * IN_DIM))[kg] = p;
  } else {  // degree count
    int e = (b - PREP_B3) * 256 + t;
    if (e < NE) atomicAdd(&deg[dst[e]], 1);
  }
}

// one-block exclusive scan over NN degrees -> offs[0..NN] and cursor copy cur[]
__global__ __launch_bounds__(1024) void scan_kernel(const int* __restrict__ deg,
                                                    int* __restrict__ offs,
                                                    int* __restrict__ cur) {
  __shared__ int part[1024];
  constexpr int NPT = 10;  // 1024*10 = 10240 >= NN
  int t = threadIdx.x;
  int base = t * NPT;
  int s = 0;
  for (int j = 0; j < NPT; ++j) {
    int n = base + j;
    s += (n < NN) ? deg[n] : 0;
  }
  part[t] = s;
  __syncthreads();
  for (int o = 1; o < 1024; o <<= 1) {  // Hillis-Steele inclusive scan
    int v = (t >= o) ? part[t - o] : 0;
    __syncthreads();
    part[t] += v;
    __syncthreads();
  }
  int pre = (t > 0) ? part[t - 1] : 0;
  for (int j = 0; j < NPT; ++j) {
    int n = base + j;
    if (n < NN) {
      offs[n] = pre;
      cur[n] = pre;
      pre += deg[n];
    }
  }
  if (t == 1023) offs[NN] = part[1023];  // == NE
}

// bin edges: csr[cur[dst]++] = src  (cur pre-seeded with offs by scan)
__global__ void bin_kernel(const int* __restrict__ src, const int* __restrict__ dst,
                           int* __restrict__ cur, int* __restrict__ csr) {
  int e = blockIdx.x * 256 + threadIdx.x;
  if (e < NE) {
    int p = atomicAdd(&cur[dst[e]], 1);
    csr[p] = src[e];
  }
}

// ---------------- layer-1 gather (bf16 source): A1 = mean_agg(x) only ----------------
__global__ __launch_bounds__(256) void gather1_kernel(unsigned short* __restrict__ x_bf,
                                                      const int* __restrict__ offs,
                                                      const int* __restrict__ csr,
                                                      unsigned short* __restrict__ A1) {
  int i = blockIdx.x;
  int t = threadIdx.x;  // 256 threads x ushort4 = 1024 bf16 = one row
  unsigned short* row = A1 + (size_t)i * 1024;
  if (i >= NN) {
    ushort4 z = {0, 0, 0, 0};
    ((ushort4*)row)[t] = z;
    ((ushort4*)(x_bf + (size_t)i * 1024))[t] = z;
    return;
  }
  int beg = offs[i], end = offs[i + 1];
  float4 a0 = {0.f, 0.f, 0.f, 0.f}, a1 = {0.f, 0.f, 0.f, 0.f};
  int j = beg;
  for (; j + 2 <= end; j += 2) {
    int s0 = __builtin_amdgcn_readfirstlane(csr[j]);
    int s1 = __builtin_amdgcn_readfirstlane(csr[j + 1]);
    ushort4 u0 = ((const ushort4*)(x_bf + (size_t)s0 * IN_DIM))[t];
    ushort4 u1 = ((const ushort4*)(x_bf + (size_t)s1 * IN_DIM))[t];
    a0.x += bf2f(u0.x); a0.y += bf2f(u0.y); a0.z += bf2f(u0.z); a0.w += bf2f(u0.w);
    a1.x += bf2f(u1.x); a1.y += bf2f(u1.y); a1.z += bf2f(u1.z); a1.w += bf2f(u1.w);
  }
  if (j < end) {
    int s0 = __builtin_amdgcn_readfirstlane(csr[j]);
    ushort4 u0 = ((const ushort4*)(x_bf + (size_t)s0 * IN_DIM))[t];
    a0.x += bf2f(u0.x); a0.y += bf2f(u0.y); a0.z += bf2f(u0.z); a0.w += bf2f(u0.w);
  }
  float inv = 1.0f / (float)max(end - beg, 1);
  ushort4 pa = {f2bf((a0.x + a1.x) * inv), f2bf((a0.y + a1.y) * inv),
                f2bf((a0.z + a1.z) * inv), f2bf((a0.w + a1.w) * inv)};
  ((ushort4*)row)[t] = pa;
}

// ---------------- GEMM1: 128x128 + counted-vmcnt pipeline (R6-verified, 219.7 us) -------
// A double-buffered (dist 1), B TRIPLE-buffered (dist 2). 80KB LDS -> 2 blocks/CU.
// Steady-state s_waitcnt vmcnt(12): newest 12 = B(t+2),A(t+1),B(t+1) stay in flight;
// tile t's loads forced complete. Raw s_barrier, no mid-loop drain-to-0.
// R7 lesson: do NOT load A fragments direct global->VGPR — the 16-row scatter
// uncoalesces (371 us, MfmaUtil 18%). A must go through global_load_lds.
__global__ __launch_bounds__(256) void gemm1_pipe_kernel(
    const unsigned short* __restrict__ A,    // A1  (k < 1024), row stride 1024
    const unsigned short* __restrict__ A2,   // x_bf (k >= 1024), row stride 1024
    const unsigned short* __restrict__ Bt,   // w1cat [4096][2048]
    const float* __restrict__ bias,
    unsigned short* __restrict__ C) {
  constexpr int BM = 128, BN = 128, BK = 64;
  constexpr int K = 2048, N = 4096;
  constexpr int NT = K / BK;  // 32
  constexpr int NUMM = 79, NUMN = 32, GM = 32, NPG = GM * NUMN;
  constexpr int TSZ = BM * BK;  // 8192 bf16 = 16KB

  __shared__ unsigned short Asm[2 * TSZ];  // 32KB
  __shared__ unsigned short Bsm[3 * TSZ];  // 48KB  (total 80KB -> 2 blocks/CU)

  const int pid = blockIdx.x;
  const int gid = pid / NPG;
  const int first_m = gid * GM;
  const int sz = (NUMM - first_m < GM) ? (NUMM - first_m) : GM;
  const int local = pid % NPG;
  const int pm = first_m + local % sz;
  const int pn = local / sz;
  const long tm0 = (long)pm * BM;
  const long tn0 = (long)pn * BN;

  const int tid = threadIdx.x;
  const int lane = tid & 63;
  const int wave = tid >> 6;
  const int quad = lane >> 4;
  const int l16 = lane & 15;
  const int l7 = l16 & 7;
  const int wm = (wave % 2) * 64;  // 2x2 wave layout
  const int wn = (wave / 2) * 64;

  f32x4 acc[4][4];
#pragma unroll
  for (int i = 0; i < 4; ++i)
#pragma unroll
    for (int j = 0; j < 4; ++j) acc[i][j] = (f32x4){0.f, 0.f, 0.f, 0.f};

  // staging map: chunk c = s*256 + tid; row r = c/8; slot = c%8;
  // source logical chunk g = slot ^ (r&7); LDS dest linear (wave-uniform + lane*16)
  size_t aOff[4], bOff[4];
#pragma unroll
  for (int s = 0; s < 4; ++s) {
    int c = s * 256 + tid;
    int r = c >> 3;
    int g = (c & 7) ^ (r & 7);
    aOff[s] = (size_t)(tm0 + r) * 1024 + g * 8;  // A row stride = K/2 = 1024 (ASPLIT)
    bOff[s] = (size_t)(tn0 + r) * K + g * 8;
  }

#define STAGE_A1(kt, ab)                                                            \
  {                                                                                 \
    const unsigned short* s_ = ((kt) < NT / 2) ? A : A2;                            \
    const int ka_ = ((kt) & (NT / 2 - 1)) * BK;                                     \
    _Pragma("unroll") for (int q_ = 0; q_ < 4; ++q_)                                \
        ld_lds16(s_ + aOff[q_] + ka_, Asm + (ab)*TSZ + q_ * 2048 + wave * 512);     \
  }
#define STAGE_B1(kt, bb)                                                            \
  {                                                                                 \
    const int k0_ = (kt)*BK;                                                        \
    _Pragma("unroll") for (int q_ = 0; q_ < 4; ++q_)                                \
        ld_lds16(Bt + bOff[q_] + k0_, Bsm + (bb)*TSZ + q_ * 2048 + wave * 512);     \
  }

  // prologue: A(0); B(0); B(1)  (B runs 2 ahead, A 1 ahead)
  STAGE_A1(0, 0)
  STAGE_B1(0, 0)
  STAGE_B1(1, 1)

  int bb = 0;  // t % 3
  for (int t = 0; t < NT; ++t) {
    if (t + 1 < NT) STAGE_A1(t + 1, (t + 1) & 1)
    if (t + 2 < NT) {
      int bb2 = bb + 2;
      if (bb2 >= 3) bb2 -= 3;
      STAGE_B1(t + 2, bb2)
    }
    if (t + 2 < NT) {
      asm volatile("s_waitcnt vmcnt(12)" ::: "memory");
    } else if (t + 1 < NT) {
      asm volatile("s_waitcnt vmcnt(8)" ::: "memory");
    } else {
      asm volatile("s_waitcnt vmcnt(0)" ::: "memory");
    }
    __builtin_amdgcn_s_barrier();          // raw: loads for t landed in ALL waves
    __builtin_amdgcn_sched_barrier(0);     // keep ds_reads below the barrier

    const unsigned short* As = Asm + (t & 1) * TSZ;
    const unsigned short* Bs = Bsm + bb * TSZ;
#pragma unroll
    for (int kk = 0; kk < 2; ++kk) {
      const int p = (kk * 4 + quad) ^ l7;
      bf16x8 af[4], bv[4];
#pragma unroll
      for (int i = 0; i < 4; ++i) af[i] = *(const bf16x8*)(As + (wm + i * 16 + l16) * BK + p * 8);
#pragma unroll
      for (int j = 0; j < 4; ++j) bv[j] = *(const bf16x8*)(Bs + (wn + j * 16 + l16) * BK + p * 8);
#pragma unroll
      for (int i = 0; i < 4; ++i)
#pragma unroll
        for (int j = 0; j < 4; ++j)
          acc[i][j] = __builtin_amdgcn_mfma_f32_16x16x32_bf16(af[i], bv[j], acc[i][j], 0, 0, 0);
    }
    __builtin_amdgcn_s_barrier();          // all reads of this tile done before overwrite
    __builtin_amdgcn_sched_barrier(0);
    bb = (bb == 2) ? 0 : bb + 1;
  }
#undef STAGE_A1
#undef STAGE_B1

  // epilogue: relu(acc + bias) -> bf16; C/D layout col = lane&15, row = quad*4 + reg
#pragma unroll
  for (int i = 0; i < 4; ++i) {
    long m0 = tm0 + wm + i * 16 + quad * 4;
#pragma unroll
    for (int j = 0; j < 4; ++j) {
      int n = (int)tn0 + wn + j * 16 + l16;
      float bvs = bias[n];
#pragma unroll
      for (int r = 0; r < 4; ++r) {
        float v = fmaxf(acc[i][j][r] + bvs, 0.0f);
        C[(size_t)(m0 + r) * N + n] = f2bf(v);
      }
    }
  }
}

// ---------------- GEMM2: 64x256 split-K=2 + same counted-vmcnt pipe (new this round) ----
// Structure clone of gemm1_pipe at GEMM2's geometry: A(h_b) + B(w2cat) double-buffered.
// Per wave per tile exactly 10 loads (2 A-chunks + 8 B-chunks) -> steady-state
// s_waitcnt vmcnt(10) retires tile t, keeps t+1's 10 in flight. LDS 80KB -> 2 blocks/CU
// (was 4 at 40KB; R6 measured the same trade as a win at GEMM1's geometry).
// Epilogue EPI=3: bf16 partial [2][M_PAD][512], slab per blockIdx.y (gather2 sums).
__global__ __launch_bounds__(256) void gemm2_pipe_kernel(
    const unsigned short* __restrict__ A,   // h_b [M_PAD][4096]
    const unsigned short* __restrict__ Bt,  // w2cat [512][4096]
    unsigned short* __restrict__ P) {
  constexpr int BM = 64, BN = 256, BK = 64;
  constexpr int K = 4096, N = 512;
  constexpr int KS = 2048;      // per split
  constexpr int NT = KS / BK;   // 32
  constexpr int ATS = BM * BK;  // 4096 shorts = 8KB
  constexpr int BTS = BN * BK;  // 16384 shorts = 32KB
  __shared__ unsigned short Asm[2 * ATS];
  __shared__ unsigned short Bsm[2 * BTS];  // total 80KB

  const int pid = blockIdx.x;   // 0..315: pm = pid>>1, pn = pid&1 (GM=1 mapping)
  const int pm = pid >> 1;
  const int pn = pid & 1;
  const int koff = (int)blockIdx.y * KS;
  const long tm0 = (long)pm * BM;
  const long tn0 = (long)pn * BN;

  const int tid = threadIdx.x;
  const int lane = tid & 63;
  const int wave = tid >> 6;
  const int quad = lane >> 4;
  const int l16 = lane & 15;
  const int l7 = l16 & 7;
  const int wn = wave * 64;  // NWY=4: each wave covers all 64 rows x its 64-col quarter

  f32x4 acc[4][4];
#pragma unroll
  for (int i = 0; i < 4; ++i)
#pragma unroll
    for (int j = 0; j < 4; ++j) acc[i][j] = (f32x4){0.f, 0.f, 0.f, 0.f};

  size_t aOff[2], bOff[8];
#pragma unroll
  for (int s = 0; s < 2; ++s) {
    int c = s * 256 + tid;
    int r = c >> 3;
    int g = (c & 7) ^ (r & 7);
    aOff[s] = (size_t)(tm0 + r) * K + koff + g * 8;
  }
#pragma unroll
  for (int s = 0; s < 8; ++s) {
    int c = s * 256 + tid;
    int r = c >> 3;
    int g = (c & 7) ^ (r & 7);
    bOff[s] = (size_t)(tn0 + r) * K + koff + g * 8;
  }

#define STAGE2(kt, buf)                                                              \
  {                                                                                  \
    const int k0_ = (kt)*BK;                                                         \
    _Pragma("unroll") for (int s_ = 0; s_ < 2; ++s_)                                 \
        ld_lds16(A + aOff[s_] + k0_, Asm + (buf)*ATS + s_ * 2048 + wave * 512);      \
    _Pragma("unroll") for (int s_ = 0; s_ < 8; ++s_)                                 \
        ld_lds16(Bt + bOff[s_] + k0_, Bsm + (buf)*BTS + s_ * 2048 + wave * 512);     \
  }

  STAGE2(0, 0)

  for (int t = 0; t < NT; ++t) {
    if (t + 1 < NT) {
      STAGE2(t + 1, (t + 1) & 1)
      asm volatile("s_waitcnt vmcnt(10)" ::: "memory");  // retire tile t; t+1 in flight
    } else {
      asm volatile("s_waitcnt vmcnt(0)" ::: "memory");
    }
    __builtin_amdgcn_s_barrier();
    __builtin_amdgcn_sched_barrier(0);

    const unsigned short* As = Asm + (t & 1) * ATS;
    const unsigned short* Bs = Bsm + (t & 1) * BTS;
#pragma unroll
    for (int kk = 0; kk < 2; ++kk) {
      const int p = (kk * 4 + quad) ^ l7;
      bf16x8 af[4], bv[4];
#pragma unroll
      for (int i = 0; i < 4; ++i) af[i] = *(const bf16x8*)(As + (i * 16 + l16) * BK + p * 8);
#pragma unroll
      for (int j = 0; j < 4; ++j) bv[j] = *(const bf16x8*)(Bs + (wn + j * 16 + l16) * BK + p * 8);
#pragma unroll
      for (int i = 0; i < 4; ++i)
#pragma unroll
        for (int j = 0; j < 4; ++j)
          acc[i][j] = __builtin_amdgcn_mfma_f32_16x16x32_bf16(af[i], bv[j], acc[i][j], 0, 0, 0);
    }
    __builtin_amdgcn_s_barrier();
    __builtin_amdgcn_sched_barrier(0);
  }
#undef STAGE2

  // epilogue: bf16 partial, slab per grid.y; C/D layout col = lane&15, row = quad*4+reg
  unsigned short* C = P + (size_t)blockIdx.y * M_PAD * 512;
#pragma unroll
  for (int i = 0; i < 4; ++i) {
    long m0 = tm0 + i * 16 + quad * 4;
#pragma unroll
    for (int j = 0; j < 4; ++j) {
      int n = (int)tn0 + wn + j * 16 + l16;
#pragma unroll
      for (int r = 0; r < 4; ++r) C[(size_t)(m0 + r) * N + n] = f2bf(acc[i][j][r]);
    }
  }
}

// ---------------- layer-2 gather + bias + p_r + log_softmax (single-wave blocks) --------
// 64 threads/block; thread t owns cols {4t..4t+3} via uint2 loads (same bytes, half the
// instructions); softmax reduction is a pure 64-wide shfl_xor butterfly — no LDS, no
// __syncthreads. Per-column accumulation order identical to the 128-thread version.
__global__ __launch_bounds__(64) void gather2_final_kernel(const unsigned short* __restrict__ P,
                                                           const int* __restrict__ offs,
                                                           const int* __restrict__ csr,
                                                           const float* __restrict__ b2,
                                                           float* __restrict__ out) {
  int i = blockIdx.x;
  int t = threadIdx.x;  // 0..63
  const unsigned short* P1 = P + (size_t)M_PAD * 512;
  int beg = offs[i], end = offs[i + 1];
  float a0 = 0.f, a1 = 0.f, a2 = 0.f, a3 = 0.f;
  int j = beg;
  for (; j + 2 <= end; j += 2) {
    int s0 = __builtin_amdgcn_readfirstlane(csr[j]);
    int s1 = __builtin_amdgcn_readfirstlane(csr[j + 1]);
    uint2 u0 = *(const uint2*)(P + (size_t)s0 * 512 + 4 * t);
    uint2 w0 = *(const uint2*)(P1 + (size_t)s0 * 512 + 4 * t);
    uint2 u1 = *(const uint2*)(P + (size_t)s1 * 512 + 4 * t);
    uint2 w1 = *(const uint2*)(P1 + (size_t)s1 * 512 + 4 * t);
    a0 += bflo(u0.x) + bflo(w0.x) + bflo(u1.x) + bflo(w1.x);
    a1 += bfhi(u0.x) + bfhi(w0.x) + bfhi(u1.x) + bfhi(w1.x);
    a2 += bflo(u0.y) + bflo(w0.y) + bflo(u1.y) + bflo(w1.y);
    a3 += bfhi(u0.y) + bfhi(w0.y) + bfhi(u1.y) + bfhi(w1.y);
  }
  if (j < end) {
    int s0 = __builtin_amdgcn_readfirstlane(csr[j]);
    uint2 u0 = *(const uint2*)(P + (size_t)s0 * 512 + 4 * t);
    uint2 w0 = *(const uint2*)(P1 + (size_t)s0 * 512 + 4 * t);
    a0 += bflo(u0.x) + bflo(w0.x);
    a1 += bfhi(u0.x) + bfhi(w0.x);
    a2 += bflo(u0.y) + bflo(w0.y);
    a3 += bfhi(u0.y) + bfhi(w0.y);
  }
  float inv = 1.0f / (float)max(end - beg, 1);
  float4 bv = ((const float4*)b2)[t];
  // self p_r term: cols 256+4t..259+4t of both partial slabs
  uint2 su = *(const uint2*)(P + (size_t)i * 512 + 256 + 4 * t);
  uint2 sw = *(const uint2*)(P1 + (size_t)i * 512 + 256 + 4 * t);
  float v0 = a0 * inv + bv.x + bflo(su.x) + bflo(sw.x);
  float v1 = a1 * inv + bv.y + bfhi(su.x) + bfhi(sw.x);
  float v2 = a2 * inv + bv.z + bflo(su.y) + bflo(sw.y);
  float v3 = a3 * inv + bv.w + bfhi(su.y) + bfhi(sw.y);

  float m = fmaxf(fmaxf(v0, v1), fmaxf(v2, v3));
#pragma unroll
  for (int o = 32; o > 0; o >>= 1) m = fmaxf(m, __shfl_xor(m, o, 64));
  float s = __expf(v0 - m) + __expf(v1 - m) + __expf(v2 - m) + __expf(v3 - m);
#pragma unroll
  for (int o = 32; o > 0; o >>= 1) s += __shfl_xor(s, o, 64);
  float ls = logf(s);

  float4 o4 = {v0 - m - ls, v1 - m - ls, v2 - m - ls, v3 - m - ls};
  ((float4*)(out + (size_t)i * OUTD))[t] = o4;
}

// ---------------- workspace layout (bytes) ----------------
static constexpr size_t OFF_A1 = 0;
static constexpr size_t OFF_XBF = OFF_A1 + (size_t)M_PAD * 1024 * 2;
static constexpr size_t OFF_W1 = OFF_XBF + (size_t)M_PAD * 1024 * 2;
static constexpr size_t OFF_HB = OFF_W1 + (size_t)HID * 2048 * 2;
static constexpr size_t OFF_W2 = OFF_HB + (size_t)M_PAD * HID * 2;
static constexpr size_t OFF_DEG = OFF_W2 + (size_t)512 * HID * 2;
static constexpr size_t OFF_OFFS = OFF_DEG + (size_t)NN * 4;
static constexpr size_t OFF_CUR = OFF_OFFS + (size_t)(NN + 4) * 4;
static constexpr size_t OFF_CSR = OFF_CUR + (size_t)NN * 4;
static constexpr size_t OFF_P = OFF_A1;  // [2][M_PAD][512] bf16 = 20.7 MB, fits A1 region

extern "C" void kernel_launch(void* const* d_in, const int* in_sizes, int n_in,
                              void* d_out, int out_size, void* d_ws, size_t ws_size,
                              hipStream_t stream) {
  const float* x = (const float*)d_in[0];
  const int* ei = (const int*)d_in[1];
  const int* src = ei;
  const int* dst = ei + NE;
  const float* W1_l = (const float*)d_in[2];
  const float* b1_l = (const float*)d_in[3];
  const float* W1_r = (const float*)d_in[4];
  const float* W2_l = (const float*)d_in[5];
  const float* b2_l = (const float*)d_in[6];
  const float* W2_r = (const float*)d_in[7];
  float* out = (float*)d_out;

  char* ws = (char*)d_ws;
  unsigned short* A1 = (unsigned short*)(ws + OFF_A1);
  unsigned short* x_bf = (unsigned short*)(ws + OFF_XBF);
  unsigned short* w1cat = (unsigned short*)(ws + OFF_W1);
  unsigned short* h_b = (unsigned short*)(ws + OFF_HB);
  unsigned short* w2cat = (unsigned short*)(ws + OFF_W2);
  int* deg = (int*)(ws + OFF_DEG);
  int* offs = (int*)(ws + OFF_OFFS);
  int* cur = (int*)(ws + OFF_CUR);
  int* csr = (int*)(ws + OFF_CSR);
  unsigned short* P = (unsigned short*)(ws + OFF_P);

  // zero degree counters (ws is poisoned 0xAA before every call)
  hipMemsetAsync(deg, 0, (size_t)NN * 4, stream);

  prep_kernel<<<PREP_NB, 256, 0, stream>>>(W1_l, W1_r, W2_l, W2_r, x, dst,
                                           w1cat, w2cat, x_bf, deg);
  scan_kernel<<<1, 1024, 0, stream>>>(deg, offs, cur);
  bin_kernel<<<(NE + 255) / 256, 256, 0, stream>>>(src, dst, cur, csr);

  gather1_kernel<<<M_PAD, 256, 0, stream>>>(x_bf, offs, csr, A1);

  // h = relu([A1 | x_bf] @ w1cat^T + b1) -> bf16 [10112][4096]  (R6 pipe, 219.7 us)
  gemm1_pipe_kernel<<<79 * 32, 256, 0, stream>>>(A1, x_bf, w1cat, b1_l, h_b);

  // split-K=2: P[s] = h[:, s*2048:(s+1)*2048] @ w2cat[:, same]^T -> bf16 [2][M][512]
  gemm2_pipe_kernel<<<dim3(158 * 2, 2), 256, 0, stream>>>(h_b, w2cat, P);

  // mean of p_l over in-edges + bias + p_r (both split-K partials), log_softmax
  gather2_final_kernel<<<NN, 64, 0, stream>>>(P, offs, csr, b2_l, out);
}

// Round 9
// 440.791 us; speedup vs baseline: 1.3584x; 1.0391x over previous
//
#include <hip/hip_runtime.h>
#include <cstdint>
#include <cstddef>

#define DEVINL __device__ __forceinline__

typedef __bf16 bf16x8 __attribute__((ext_vector_type(8)));
typedef float f32x4 __attribute__((ext_vector_type(4)));

static constexpr int NN = 10000;     // nodes
static constexpr int NE = 80000;     // edges
static constexpr int IN_DIM = 1024;
static constexpr int HID = 4096;
static constexpr int OUTD = 256;
static constexpr int M_PAD = 10112;  // 79*128 (also 158*64)

// fp32 -> bf16 round-nearest-even
DEVINL unsigned short f2bf(float f) {
  unsigned int u = __builtin_bit_cast(unsigned int, f);
  u += 0x7fffu + ((u >> 16) & 1u);
  return (unsigned short)(u >> 16);
}
DEVINL float bf2f(unsigned short h) {
  unsigned int u = ((unsigned int)h) << 16;
  return __builtin_bit_cast(float, u);
}

// async global->LDS, 16B per lane; LDS dest is wave-uniform base + lane*16
DEVINL void ld_lds16(const void* g, void* l) {
  __builtin_amdgcn_global_load_lds(
      (const __attribute__((address_space(1))) unsigned int*)g,
      (__attribute__((address_space(3))) unsigned int*)l, 16, 0, 0);
}

// ---------------- fused prep: conv_w1 + conv_w2 + x->bf16 + degree count ----------------
static constexpr int PREP_B1 = 8192;
static constexpr int PREP_B2 = PREP_B1 + 2048;
static constexpr int PREP_B3 = PREP_B2 + 10000;
static constexpr int PREP_NB = PREP_B3 + 313;

__global__ __launch_bounds__(256) void prep_kernel(
    const float* __restrict__ W1l, const float* __restrict__ W1r,
    const float* __restrict__ W2l, const float* __restrict__ W2r,
    const float* __restrict__ x, const int* __restrict__ dst,
    unsigned short* __restrict__ w1cat, unsigned short* __restrict__ w2cat,
    unsigned short* __restrict__ x_bf, int* __restrict__ deg) {
  int b = blockIdx.x;
  int t = threadIdx.x;
  if (b < PREP_B1) {  // w1cat [4096][2048]: row n = [W1_l row n | W1_r row n]
    int g = b * 256 + t;
    int n = g >> 9;
    int kg = g & 511;
    const float* s = (kg < 256) ? (W1l + (size_t)n * 1024 + kg * 4)
                                : (W1r + (size_t)n * 1024 + (kg - 256) * 4);
    float4 v = *(const float4*)s;
    ushort4 p = {f2bf(v.x), f2bf(v.y), f2bf(v.z), f2bf(v.w)};
    ((ushort4*)w1cat)[g] = p;
  } else if (b < PREP_B2) {  // w2cat [512][4096]: rows 0..255 = W2_l, 256..511 = W2_r
    int g = (b - PREP_B1) * 256 + t;
    int n = g >> 10;
    int kg = g & 1023;
    const float* s = (n < 256) ? (W2l + (size_t)n * 4096 + kg * 4)
                               : (W2r + (size_t)(n - 256) * 4096 + kg * 4);
    float4 v = *(const float4*)s;
    ushort4 p = {f2bf(v.x), f2bf(v.y), f2bf(v.z), f2bf(v.w)};
    ((ushort4*)w2cat)[g] = p;
  } else if (b < PREP_B3) {  // x -> bf16, [10000][1024]
    int g = (b - PREP_B2) * 256 + t;
    int i = g >> 8;
    int kg = g & 255;
    float4 v = ((const float4*)(x + (size_t)i * IN_DIM))[kg];
    ushort4 p = {f2bf(v.x), f2bf(v.y), f2bf(v.z), f2bf(v.w)};
    ((ushort4*)(x_bf + (size_t)i * IN_DIM))[kg] = p;
  } else {  // degree count
    int e = (b - PREP_B3) * 256 + t;
    if (e < NE) atomicAdd(&deg[dst[e]], 1);
  }
}

// one-block exclusive scan over NN degrees -> offs[0..NN] and cursor copy cur[]
__global__ __launch_bounds__(1024) void scan_kernel(const int* __restrict__ deg,
                                                    int* __restrict__ offs,
                                                    int* __restrict__ cur) {
  __shared__ int part[1024];
  constexpr int NPT = 10;  // 1024*10 = 10240 >= NN
  int t = threadIdx.x;
  int base = t * NPT;
  int s = 0;
  for (int j = 0; j < NPT; ++j) {
    int n = base + j;
    s += (n < NN) ? deg[n] : 0;
  }
  part[t] = s;
  __syncthreads();
  for (int o = 1; o < 1024; o <<= 1) {  // Hillis-Steele inclusive scan
    int v = (t >= o) ? part[t - o] : 0;
    __syncthreads();
    part[t] += v;
    __syncthreads();
  }
  int pre = (t > 0) ? part[t - 1] : 0;
  for (int j = 0; j < NPT; ++j) {
    int n = base + j;
    if (n < NN) {
      offs[n] = pre;
      cur[n] = pre;
      pre += deg[n];
    }
  }
  if (t == 1023) offs[NN] = part[1023];  // == NE
}

// bin edges: csr[cur[dst]++] = src  (cur pre-seeded with offs by scan)
__global__ void bin_kernel(const int* __restrict__ src, const int* __restrict__ dst,
                           int* __restrict__ cur, int* __restrict__ csr) {
  int e = blockIdx.x * 256 + threadIdx.x;
  if (e < NE) {
    int p = atomicAdd(&cur[dst[e]], 1);
    csr[p] = src[e];
  }
}

// ---------------- layer-1 gather (bf16 source): A1 = mean_agg(x) only ----------------
__global__ __launch_bounds__(256) void gather1_kernel(unsigned short* __restrict__ x_bf,
                                                      const int* __restrict__ offs,
                                                      const int* __restrict__ csr,
                                                      unsigned short* __restrict__ A1) {
  int i = blockIdx.x;
  int t = threadIdx.x;  // 256 threads x ushort4 = 1024 bf16 = one row
  unsigned short* row = A1 + (size_t)i * 1024;
  if (i >= NN) {
    ushort4 z = {0, 0, 0, 0};
    ((ushort4*)row)[t] = z;
    ((ushort4*)(x_bf + (size_t)i * 1024))[t] = z;
    return;
  }
  int beg = offs[i], end = offs[i + 1];
  float4 a0 = {0.f, 0.f, 0.f, 0.f}, a1 = {0.f, 0.f, 0.f, 0.f};
  int j = beg;
  for (; j + 2 <= end; j += 2) {
    int s0 = __builtin_amdgcn_readfirstlane(csr[j]);
    int s1 = __builtin_amdgcn_readfirstlane(csr[j + 1]);
    ushort4 u0 = ((const ushort4*)(x_bf + (size_t)s0 * IN_DIM))[t];
    ushort4 u1 = ((const ushort4*)(x_bf + (size_t)s1 * IN_DIM))[t];
    a0.x += bf2f(u0.x); a0.y += bf2f(u0.y); a0.z += bf2f(u0.z); a0.w += bf2f(u0.w);
    a1.x += bf2f(u1.x); a1.y += bf2f(u1.y); a1.z += bf2f(u1.z); a1.w += bf2f(u1.w);
  }
  if (j < end) {
    int s0 = __builtin_amdgcn_readfirstlane(csr[j]);
    ushort4 u0 = ((const ushort4*)(x_bf + (size_t)s0 * IN_DIM))[t];
    a0.x += bf2f(u0.x); a0.y += bf2f(u0.y); a0.z += bf2f(u0.z); a0.w += bf2f(u0.w);
  }
  float inv = 1.0f / (float)max(end - beg, 1);
  ushort4 pa = {f2bf((a0.x + a1.x) * inv), f2bf((a0.y + a1.y) * inv),
                f2bf((a0.z + a1.z) * inv), f2bf((a0.w + a1.w) * inv)};
  ((ushort4*)row)[t] = pa;
}

// ---------------- GEMM1: 128x128 + counted-vmcnt pipeline (R6-verified, 219.7 us) -------
// A double-buffered (dist 1), B TRIPLE-buffered (dist 2). 80KB LDS -> 2 blocks/CU.
// Steady-state s_waitcnt vmcnt(12): newest 12 = B(t+2),A(t+1),B(t+1) stay in flight;
// tile t's loads forced complete. Raw s_barrier, no mid-loop drain-to-0.
// Session ledger: 256^2 phase-splits -9%/-4% (R3/R4); A-direct-to-reg -69% (R7:
// 16-row scatter uncoalesces — A must go through global_load_lds); deep-LDS pipe on
// GEMM2 -7% (R8: 632-block grid can't amortize the 2-blocks/CU residency tail —
// deep pipelines only pay when blocks >> capacity, GEMM1 has 2528).
__global__ __launch_bounds__(256) void gemm1_pipe_kernel(
    const unsigned short* __restrict__ A,    // A1  (k < 1024), row stride 1024
    const unsigned short* __restrict__ A2,   // x_bf (k >= 1024), row stride 1024
    const unsigned short* __restrict__ Bt,   // w1cat [4096][2048]
    const float* __restrict__ bias,
    unsigned short* __restrict__ C) {
  constexpr int BM = 128, BN = 128, BK = 64;
  constexpr int K = 2048, N = 4096;
  constexpr int NT = K / BK;  // 32
  constexpr int NUMM = 79, NUMN = 32, GM = 32, NPG = GM * NUMN;
  constexpr int TSZ = BM * BK;  // 8192 bf16 = 16KB

  __shared__ unsigned short Asm[2 * TSZ];  // 32KB
  __shared__ unsigned short Bsm[3 * TSZ];  // 48KB  (total 80KB -> 2 blocks/CU)

  const int pid = blockIdx.x;
  const int gid = pid / NPG;
  const int first_m = gid * GM;
  const int sz = (NUMM - first_m < GM) ? (NUMM - first_m) : GM;
  const int local = pid % NPG;
  const int pm = first_m + local % sz;
  const int pn = local / sz;
  const long tm0 = (long)pm * BM;
  const long tn0 = (long)pn * BN;

  const int tid = threadIdx.x;
  const int lane = tid & 63;
  const int wave = tid >> 6;
  const int quad = lane >> 4;
  const int l16 = lane & 15;
  const int l7 = l16 & 7;
  const int wm = (wave % 2) * 64;  // 2x2 wave layout
  const int wn = (wave / 2) * 64;

  f32x4 acc[4][4];
#pragma unroll
  for (int i = 0; i < 4; ++i)
#pragma unroll
    for (int j = 0; j < 4; ++j) acc[i][j] = (f32x4){0.f, 0.f, 0.f, 0.f};

  // staging map: chunk c = s*256 + tid; row r = c/8; slot = c%8;
  // source logical chunk g = slot ^ (r&7); LDS dest linear (wave-uniform + lane*16)
  size_t aOff[4], bOff[4];
#pragma unroll
  for (int s = 0; s < 4; ++s) {
    int c = s * 256 + tid;
    int r = c >> 3;
    int g = (c & 7) ^ (r & 7);
    aOff[s] = (size_t)(tm0 + r) * 1024 + g * 8;  // A row stride = K/2 = 1024 (ASPLIT)
    bOff[s] = (size_t)(tn0 + r) * K + g * 8;
  }

#define STAGE_A1(kt, ab)                                                            \
  {                                                                                 \
    const unsigned short* s_ = ((kt) < NT / 2) ? A : A2;                            \
    const int ka_ = ((kt) & (NT / 2 - 1)) * BK;                                     \
    _Pragma("unroll") for (int q_ = 0; q_ < 4; ++q_)                                \
        ld_lds16(s_ + aOff[q_] + ka_, Asm + (ab)*TSZ + q_ * 2048 + wave * 512);     \
  }
#define STAGE_B1(kt, bb)                                                            \
  {                                                                                 \
    const int k0_ = (kt)*BK;                                                        \
    _Pragma("unroll") for (int q_ = 0; q_ < 4; ++q_)                                \
        ld_lds16(Bt + bOff[q_] + k0_, Bsm + (bb)*TSZ + q_ * 2048 + wave * 512);     \
  }

  // prologue: A(0); B(0); B(1)  (B runs 2 ahead, A 1 ahead)
  STAGE_A1(0, 0)
  STAGE_B1(0, 0)
  STAGE_B1(1, 1)

  int bb = 0;  // t % 3
  for (int t = 0; t < NT; ++t) {
    if (t + 1 < NT) STAGE_A1(t + 1, (t + 1) & 1)
    if (t + 2 < NT) {
      int bb2 = bb + 2;
      if (bb2 >= 3) bb2 -= 3;
      STAGE_B1(t + 2, bb2)
    }
    if (t + 2 < NT) {
      asm volatile("s_waitcnt vmcnt(12)" ::: "memory");
    } else if (t + 1 < NT) {
      asm volatile("s_waitcnt vmcnt(8)" ::: "memory");
    } else {
      asm volatile("s_waitcnt vmcnt(0)" ::: "memory");
    }
    __builtin_amdgcn_s_barrier();          // raw: loads for t landed in ALL waves
    __builtin_amdgcn_sched_barrier(0);     // keep ds_reads below the barrier

    const unsigned short* As = Asm + (t & 1) * TSZ;
    const unsigned short* Bs = Bsm + bb * TSZ;
#pragma unroll
    for (int kk = 0; kk < 2; ++kk) {
      const int p = (kk * 4 + quad) ^ l7;
      bf16x8 af[4], bv[4];
#pragma unroll
      for (int i = 0; i < 4; ++i) af[i] = *(const bf16x8*)(As + (wm + i * 16 + l16) * BK + p * 8);
#pragma unroll
      for (int j = 0; j < 4; ++j) bv[j] = *(const bf16x8*)(Bs + (wn + j * 16 + l16) * BK + p * 8);
#pragma unroll
      for (int i = 0; i < 4; ++i)
#pragma unroll
        for (int j = 0; j < 4; ++j)
          acc[i][j] = __builtin_amdgcn_mfma_f32_16x16x32_bf16(af[i], bv[j], acc[i][j], 0, 0, 0);
    }
    __builtin_amdgcn_s_barrier();          // all reads of this tile done before overwrite
    __builtin_amdgcn_sched_barrier(0);
    bb = (bb == 2) ? 0 : bb + 1;
  }
#undef STAGE_A1
#undef STAGE_B1

  // epilogue: relu(acc + bias) -> bf16; C/D layout col = lane&15, row = quad*4 + reg
#pragma unroll
  for (int i = 0; i < 4; ++i) {
    long m0 = tm0 + wm + i * 16 + quad * 4;
#pragma unroll
    for (int j = 0; j < 4; ++j) {
      int n = (int)tn0 + wn + j * 16 + l16;
      float bvs = bias[n];
#pragma unroll
      for (int r = 0; r < 4; ++r) {
        float v = fmaxf(acc[i][j][r] + bvs, 0.0f);
        C[(size_t)(m0 + r) * N + n] = f2bf(v);
      }
    }
  }
}

// ---------------- bf16 MFMA GEMM, templated (kept for GEMM2) ----------------
// NOTE (R5): BM 64->32 for GEMM2 regressed (~+15 us). Keep BM=64.
// NOTE (R8): deep-LDS counted-vmcnt pipe for GEMM2 regressed (~+10-15 us): 80KB LDS
// halves blocks/CU to 2 -> 632-block grid becomes a 512+120 two-round execution with
// a ~23%-occupied tail. At 40KB all 632 blocks are co-resident. Keep this template.
template <int BM, int BN, int BK, int K, int KSPLIT, int N, int NUMM, int NUMN, int GM,
          int EPI, int NWY, bool ASPLIT>
__global__ __launch_bounds__(256) void gemm_kernel(const unsigned short* __restrict__ A,
                                                   const unsigned short* __restrict__ A2,
                                                   const unsigned short* __restrict__ Bt,
                                                   const float* __restrict__ bias,
                                                   void* __restrict__ C0out) {
  constexpr int MGR = 4 / NWY;            // waves along m
  constexpr int MI = BM / 16 / MGR;       // 16-row tiles per wave
  constexpr int NI = 4;                   // 16-col tiles per wave (BN = NWY*64)
  constexpr int CPR = BK / 8;             // 16B chunks per LDS row
  constexpr int SA = BM * CPR / 256;      // staging rounds for A (256 thr x 16B)
  constexpr int SB = BN * CPR / 256;
  constexpr int KK = BK / 32;             // MFMA k-steps per tile
  constexpr int KS = K / KSPLIT;          // K range per split
  constexpr int AS = ASPLIT ? K / 2 : K;  // A row stride
  __shared__ unsigned short Asm[BM * BK];
  __shared__ unsigned short Bsm[BN * BK];

  constexpr int NPG = GM * NUMN;
  const int pid = blockIdx.x;
  const int gid = pid / NPG;
  const int first_m = gid * GM;
  const int sz = (NUMM - first_m < GM) ? (NUMM - first_m) : GM;
  const int local = pid % NPG;
  const int pm = first_m + local % sz;
  const int pn = local / sz;
  const int koff = (KSPLIT > 1) ? (int)blockIdx.y * KS : 0;

  const int tid = threadIdx.x;
  const int lane = tid & 63;
  const int wave = tid >> 6;
  const int quad = lane >> 4;
  const int l16 = lane & 15;
  const int wm = (wave % MGR) * (BM / MGR);
  const int wn = (wave / MGR) * 64;
  const long tm0 = (long)pm * BM;
  const long tn0 = (long)pn * BN;

  f32x4 acc[MI][NI];
#pragma unroll
  for (int i = 0; i < MI; ++i)
#pragma unroll
    for (int j = 0; j < NI; ++j) acc[i][j] = (f32x4){0.f, 0.f, 0.f, 0.f};

  size_t aOff[SA];
  unsigned short* aDst[SA];
  const unsigned short* bSrc[SB];
  unsigned short* bDst[SB];
#pragma unroll
  for (int s = 0; s < SA; ++s) {
    int c = s * 256 + wave * 64 + lane;
    int r = c / CPR;
    int g = (c % CPR) ^ (r & 7);
    aOff[s] = (size_t)(tm0 + r) * AS + koff + g * 8;
    aDst[s] = Asm + s * 2048 + wave * 512;  // wave-uniform base
  }
#pragma unroll
  for (int s = 0; s < SB; ++s) {
    int c = s * 256 + wave * 64 + lane;
    int r = c / CPR;
    int g = (c % CPR) ^ (r & 7);
    bSrc[s] = Bt + (size_t)(tn0 + r) * K + koff + g * 8;
    bDst[s] = Bsm + s * 2048 + wave * 512;
  }

  const int l7 = l16 & 7;

  for (int k0 = 0; k0 < KS; k0 += BK) {
    const unsigned short* ab = (!ASPLIT || k0 < K / 2) ? A : A2;
    const int ka = ASPLIT ? (k0 & (K / 2 - 1)) : k0;
#pragma unroll
    for (int s = 0; s < SA; ++s) ld_lds16(ab + aOff[s] + ka, aDst[s]);
#pragma unroll
    for (int s = 0; s < SB; ++s) ld_lds16(bSrc[s] + k0, bDst[s]);
    __syncthreads();  // drains vmcnt -> LDS tiles complete

#pragma unroll
    for (int kk = 0; kk < KK; ++kk) {
      const int p = (kk * 4 + quad) ^ l7;  // physical chunk for this frag
      bf16x8 af[MI], bv[NI];
#pragma unroll
      for (int i = 0; i < MI; ++i) {
        int ra = wm + i * 16 + l16;
        af[i] = *(const bf16x8*)(Asm + ra * BK + p * 8);
      }
#pragma unroll
      for (int j = 0; j < NI; ++j) {
        int rb = wn + j * 16 + l16;
        bv[j] = *(const bf16x8*)(Bsm + rb * BK + p * 8);
      }
#pragma unroll
      for (int i = 0; i < MI; ++i)
#pragma unroll
        for (int j = 0; j < NI; ++j)
          acc[i][j] = __builtin_amdgcn_mfma_f32_16x16x32_bf16(af[i], bv[j], acc[i][j], 0, 0, 0);
    }
    __syncthreads();  // LDS reads done before next stage overwrites
  }

  if (EPI == 1) {
    unsigned short* C = (unsigned short*)C0out;
#pragma unroll
    for (int i = 0; i < MI; ++i) {
      long m0 = tm0 + wm + i * 16 + quad * 4;
#pragma unroll
      for (int j = 0; j < NI; ++j) {
        int n = (int)tn0 + wn + j * 16 + l16;
        float bvs = bias[n];
#pragma unroll
        for (int r = 0; r < 4; ++r) {
          float v = acc[i][j][r] + bvs;
          v = fmaxf(v, 0.0f);
          C[(size_t)(m0 + r) * N + n] = f2bf(v);
        }
      }
    }
  } else {  // EPI == 3: bf16 partial, slab per grid.y
    unsigned short* C = (unsigned short*)C0out + (size_t)blockIdx.y * NUMM * BM * N;
#pragma unroll
    for (int i = 0; i < MI; ++i) {
      long m0 = tm0 + wm + i * 16 + quad * 4;
#pragma unroll
      for (int j = 0; j < NI; ++j) {
        int n = (int)tn0 + wn + j * 16 + l16;
#pragma unroll
        for (int r = 0; r < 4; ++r) C[(size_t)(m0 + r) * N + n] = f2bf(acc[i][j][r]);
      }
    }
  }
}

// ---------------- layer-2 gather + bias + p_r + log_softmax (fused, reads split-K P) ----
__global__ __launch_bounds__(128) void gather2_final_kernel(const unsigned short* __restrict__ P,
                                                            const int* __restrict__ offs,
                                                            const int* __restrict__ csr,
                                                            const float* __restrict__ b2,
                                                            float* __restrict__ out) {
  int i = blockIdx.x;
  int t = threadIdx.x;  // 0..127
  const unsigned short* P1 = P + (size_t)M_PAD * 512;
  int beg = offs[i], end = offs[i + 1];
  float a0 = 0.f, a1 = 0.f, c0 = 0.f, c1 = 0.f;
  int j = beg;
  for (; j + 2 <= end; j += 2) {
    int s0 = __builtin_amdgcn_readfirstlane(csr[j]);
    int s1 = __builtin_amdgcn_readfirstlane(csr[j + 1]);
    unsigned int u0 = ((const unsigned int*)(P + (size_t)s0 * 512))[t];
    unsigned int w0 = ((const unsigned int*)(P1 + (size_t)s0 * 512))[t];
    unsigned int u1 = ((const unsigned int*)(P + (size_t)s1 * 512))[t];
    unsigned int w1 = ((const unsigned int*)(P1 + (size_t)s1 * 512))[t];
    a0 += bf2f((unsigned short)(u0 & 0xffffu)) + bf2f((unsigned short)(w0 & 0xffffu));
    a1 += bf2f((unsigned short)(u0 >> 16)) + bf2f((unsigned short)(w0 >> 16));
    c0 += bf2f((unsigned short)(u1 & 0xffffu)) + bf2f((unsigned short)(w1 & 0xffffu));
    c1 += bf2f((unsigned short)(u1 >> 16)) + bf2f((unsigned short)(w1 >> 16));
  }
  if (j < end) {
    int s0 = __builtin_amdgcn_readfirstlane(csr[j]);
    unsigned int u0 = ((const unsigned int*)(P + (size_t)s0 * 512))[t];
    unsigned int w0 = ((const unsigned int*)(P1 + (size_t)s0 * 512))[t];
    a0 += bf2f((unsigned short)(u0 & 0xffffu)) + bf2f((unsigned short)(w0 & 0xffffu));
    a1 += bf2f((unsigned short)(u0 >> 16)) + bf2f((unsigned short)(w0 >> 16));
  }
  float inv = 1.0f / (float)max(end - beg, 1);
  float2 bv = ((const float2*)b2)[t];
  // self p_r term: cols 256+2t, 257+2t of both partial slabs
  unsigned int su = ((const unsigned int*)(P + (size_t)i * 512))[128 + t];
  unsigned int sw = ((const unsigned int*)(P1 + (size_t)i * 512))[128 + t];
  float pv0 = bf2f((unsigned short)(su & 0xffffu)) + bf2f((unsigned short)(sw & 0xffffu));
  float pv1 = bf2f((unsigned short)(su >> 16)) + bf2f((unsigned short)(sw >> 16));
  float v0 = (a0 + c0) * inv + bv.x + pv0;
  float v1 = (a1 + c1) * inv + bv.y + pv1;

  __shared__ float sm[2], ss[2];
  int w = t >> 6;
  float m = fmaxf(v0, v1);
#pragma unroll
  for (int o = 32; o > 0; o >>= 1) m = fmaxf(m, __shfl_xor(m, o, 64));
  if ((t & 63) == 0) sm[w] = m;
  __syncthreads();
  m = fmaxf(sm[0], sm[1]);

  float s = __expf(v0 - m) + __expf(v1 - m);
#pragma unroll
  for (int o = 32; o > 0; o >>= 1) s += __shfl_xor(s, o, 64);
  if ((t & 63) == 0) ss[w] = s;
  __syncthreads();
  float ls = logf(ss[0] + ss[1]);

  float2 o2 = {v0 - m - ls, v1 - m - ls};
  ((float2*)(out + (size_t)i * OUTD))[t] = o2;
}

// ---------------- workspace layout (bytes) ----------------
static constexpr size_t OFF_A1 = 0;
static constexpr size_t OFF_XBF = OFF_A1 + (size_t)M_PAD * 1024 * 2;
static constexpr size_t OFF_W1 = OFF_XBF + (size_t)M_PAD * 1024 * 2;
static constexpr size_t OFF_HB = OFF_W1 + (size_t)HID * 2048 * 2;
static constexpr size_t OFF_W2 = OFF_HB + (size_t)M_PAD * HID * 2;
static constexpr size_t OFF_DEG = OFF_W2 + (size_t)512 * HID * 2;
static constexpr size_t OFF_OFFS = OFF_DEG + (size_t)NN * 4;
static constexpr size_t OFF_CUR = OFF_OFFS + (size_t)(NN + 4) * 4;
static constexpr size_t OFF_CSR = OFF_CUR + (size_t)NN * 4;
static constexpr size_t OFF_P = OFF_A1;  // [2][M_PAD][512] bf16 = 20.7 MB, fits A1 region

extern "C" void kernel_launch(void* const* d_in, const int* in_sizes, int n_in,
                              void* d_out, int out_size, void* d_ws, size_t ws_size,
                              hipStream_t stream) {
  const float* x = (const float*)d_in[0];
  const int* ei = (const int*)d_in[1];
  const int* src = ei;
  const int* dst = ei + NE;
  const float* W1_l = (const float*)d_in[2];
  const float* b1_l = (const float*)d_in[3];
  const float* W1_r = (const float*)d_in[4];
  const float* W2_l = (const float*)d_in[5];
  const float* b2_l = (const float*)d_in[6];
  const float* W2_r = (const float*)d_in[7];
  float* out = (float*)d_out;

  char* ws = (char*)d_ws;
  unsigned short* A1 = (unsigned short*)(ws + OFF_A1);
  unsigned short* x_bf = (unsigned short*)(ws + OFF_XBF);
  unsigned short* w1cat = (unsigned short*)(ws + OFF_W1);
  unsigned short* h_b = (unsigned short*)(ws + OFF_HB);
  unsigned short* w2cat = (unsigned short*)(ws + OFF_W2);
  int* deg = (int*)(ws + OFF_DEG);
  int* offs = (int*)(ws + OFF_OFFS);
  int* cur = (int*)(ws + OFF_CUR);
  int* csr = (int*)(ws + OFF_CSR);
  unsigned short* P = (unsigned short*)(ws + OFF_P);

  // zero degree counters (ws is poisoned 0xAA before every call)
  hipMemsetAsync(deg, 0, (size_t)NN * 4, stream);

  prep_kernel<<<PREP_NB, 256, 0, stream>>>(W1_l, W1_r, W2_l, W2_r, x, dst,
                                           w1cat, w2cat, x_bf, deg);
  scan_kernel<<<1, 1024, 0, stream>>>(deg, offs, cur);
  bin_kernel<<<(NE + 255) / 256, 256, 0, stream>>>(src, dst, cur, csr);

  gather1_kernel<<<M_PAD, 256, 0, stream>>>(x_bf, offs, csr, A1);

  // h = relu([A1 | x_bf] @ w1cat^T + b1) -> bf16 [10112][4096]
  // baseline 128^2 geometry + counted-vmcnt A-dbuf/B-tribuf pipeline (80KB LDS)
  gemm1_pipe_kernel<<<79 * 32, 256, 0, stream>>>(A1, x_bf, w1cat, b1_l, h_b);

  // split-K=2, BM=64 (R2-verified config): P[s] -> bf16 [2][M][512]
  gemm_kernel<64, 256, 64, 4096, 2, 512, 158, 2, 1, 3, 4, false>
      <<<dim3(158 * 2, 2), 256, 0, stream>>>(h_b, nullptr, w2cat, nullptr, P);

  gather2_final_kernel<<<NN, 128, 0, stream>>>(P, offs, csr, b2_l, out);
}